// Round 2
// baseline (395.115 us; speedup 1.0000x reference)
//
#include <hip/hip_runtime.h>

// ---------------------------------------------------------------------------
// DensityMatrixMLP: out[b] = (L Lt) / trace(L Lt),  L = tril(relu(x@W1+b1)@W2+b2)
// B=131072, IN=256, HID=128, TRIL=136, D=16.
//
// R1: VALU epilogue was issue-bound (152us). R2: LL^T via MFMA (A-frag==B-frag
// identity), one barrier, 95us/dispatch but phase-locked: HBM reads all in
// GEMM1, writes all in LL^T, HBM idle in between (2.4 TB/s avg, 6% MFMA).
// R3 (container flake; hardened here as R3b): break the phase lockstep.
//   - The two m-tiles are fully independent: pipeline them. First 4 k-steps
//     of mt1's x (xp[8] = 32 VGPR, not 64 -> stays under the 128-VGPR cap of
//     __launch_bounds__(256,4)) are issued right after GEMM2(mt0)'s MFMAs;
//     the rest roll inside GEMM1(mt1). Reads overlap mt0's compute+stores.
//   - mt0's x uses a rolling 4-deep prefetch window (256B/lane in flight).
//   - No __syncthreads(): LDS is per-wave, per-mt regions (16 rows x 160
//     halves); within-wave visibility via the in-order DS pipe (same
//     property R2 relied on for scatter->LL^T).
// ---------------------------------------------------------------------------

typedef _Float16 h8 __attribute__((ext_vector_type(8)));
typedef float    f4 __attribute__((ext_vector_type(4)));
typedef int      i2 __attribute__((ext_vector_type(2)));

#define BATCH_N 131072
#define IN_DIM  256
#define HID     128
#define TRILN   136
#define BM      128      // batch rows per block (4 waves x 2 m-tiles of 16)
#define NT1     8        // 128/16 n-tiles, GEMM1
#define KS1     8        // 256/32 k-steps, GEMM1
#define NT2     9        // ceil(136/16) n-tiles, GEMM2 (padded with zeros)
#define KS2     4        // 128/32 k-steps, GEMM2
#define HSTR    136      // h LDS row stride (halves) inside an mt region
#define LVSTR   160      // v LDS row stride (halves): 16 tril rows padded to
                         // 4-half multiples -> every L-row starts 8B-aligned
#define MTREG   2560     // halves per (wave, mt) region: 16 rows x LVSTR
#define PW1_N   (KS1*NT1*64*8)   // 32768 halves = 64 KB
#define PW2_N   (KS2*NT2*64*8)   // 18432 halves = 36 KB

// offset (halves) of tril row i inside a batch row's LVSTR region:
// rows padded to 4*ceil((i+1)/4); closed form via group g=i>>2.
__device__ __forceinline__ int rowoff(int i) {
    int g = i >> 2;
    return 4 * (g + 1) * (2 * g + (i & 3));   // 0,4,8,12,16,24,...,144
}

// ---------------------------------------------------------------------------
// Prelude: pack W1/W2 into MFMA B-fragment order, fp16.
// ---------------------------------------------------------------------------
__global__ void pack_weights(const float* __restrict__ W1,
                             const float* __restrict__ W2,
                             _Float16* __restrict__ pw1,
                             _Float16* __restrict__ pw2) {
    int gid = blockIdx.x * blockDim.x + threadIdx.x;
    if (gid < PW1_N) {
        int j = gid & 7, l = (gid >> 3) & 63, f = gid >> 9;
        int ks = f >> 3, nt = f & 7;
        int k = ks * 32 + (l >> 4) * 8 + j;
        int n = nt * 16 + (l & 15);
        pw1[gid] = (_Float16)W1[k * HID + n];
    } else if (gid < PW1_N + PW2_N) {
        int g = gid - PW1_N;
        int j = g & 7, l = (g >> 3) & 63, f = g >> 9;
        int ks = f / NT2, nt = f - ks * NT2;
        int k = ks * 32 + (l >> 4) * 8 + j;
        int col = nt * 16 + (l & 15);
        pw2[g] = (col < TRILN) ? (_Float16)W2[k * TRILN + col] : (_Float16)0.0f;
    }
}

__device__ __forceinline__ h8 cvt_h8(f4 lo, f4 hi) {
    h8 r;
    r[0] = (_Float16)lo[0]; r[1] = (_Float16)lo[1];
    r[2] = (_Float16)lo[2]; r[3] = (_Float16)lo[3];
    r[4] = (_Float16)hi[0]; r[5] = (_Float16)hi[1];
    r[6] = (_Float16)hi[2]; r[7] = (_Float16)hi[3];
    return r;
}

// Per-mt tail: h->LDS, GEMM2, (mt0: issue mt1 x window), trace, scatter, LL^T.
// MTBASE: this (wave,mt)'s LDS region. MT: 0 or 1 (literal).
#define TAIL(MTBASE, MT)                                                       \
  do {                                                                         \
    /* bias + relu + store h (own wave's rows -> in-order DS suffices) */      \
    _Pragma("unroll")                                                          \
    for (int nt = 0; nt < NT1; ++nt) {                                         \
      float b1v = b1[nt * 16 + lm];                                            \
      _Pragma("unroll")                                                        \
      for (int r = 0; r < 4; ++r) {                                            \
        float hv = fmaxf(acc[nt][r] + b1v, 0.f);                               \
        (MTBASE)[(q * 4 + r) * HSTR + nt * 16 + lm] = (_Float16)hv;            \
      }                                                                        \
    }                                                                          \
    /* GEMM2: v = h @ W2 */                                                    \
    f4 acc2[NT2];                                                              \
    _Pragma("unroll")                                                          \
    for (int nt = 0; nt < NT2; ++nt) acc2[nt] = (f4){0.f, 0.f, 0.f, 0.f};      \
    _Pragma("unroll")                                                          \
    for (int ks = 0; ks < KS2; ++ks) {                                         \
      h8 ha = *(const h8*)((MTBASE) + lm * HSTR + ks * 32 + q * 8);            \
      _Pragma("unroll")                                                        \
      for (int nt = 0; nt < NT2; ++nt) {                                       \
        h8 bf2 = *(const h8*)(pw2 + ((ks * NT2 + nt) * 64 + lane) * 8);        \
        acc2[nt] = __builtin_amdgcn_mfma_f32_16x16x32_f16(ha, bf2, acc2[nt], 0, 0, 0); \
      }                                                                        \
    }                                                                          \
    if ((MT) == 0) {                                                           \
      /* issue the first 4 k-steps of mt1's x now: overlaps trace/scatter/  */ \
      /* LL^T and the out-stores below. sched_barrier pins the issue point. */ \
      _Pragma("unroll")                                                        \
      for (int k = 0; k < 4; ++k) {                                            \
        xp[2 * k]     = *(const f4*)(xr1 + k * 32);                            \
        xp[2 * k + 1] = *(const f4*)(xr1 + k * 32 + 4);                        \
      }                                                                        \
      __builtin_amdgcn_sched_barrier(0);                                       \
    }                                                                          \
    /* bias2 + per-lane tril mapping */                                        \
    float b2v[NT2];                                                            \
    int voff[NT2]; bool vok[NT2];                                              \
    _Pragma("unroll")                                                          \
    for (int nt = 0; nt < NT2; ++nt) {                                         \
      int c = nt * 16 + lm;                                                    \
      vok[nt] = (c < TRILN);                                                   \
      int cc = vok[nt] ? c : 0;                                                \
      int i = (int)((sqrtf(8.0f * (float)cc + 1.0f) - 1.0f) * 0.5f);           \
      int k = cc - (i * (i + 1)) / 2;                                          \
      voff[nt] = rowoff(i) + k;                                                \
      b2v[nt] = vok[nt] ? b2[c] : 0.f;                                         \
    }                                                                          \
    /* trace partials from registers, reduce across the 16-lane row group */   \
    float rinv[4];                                                             \
    _Pragma("unroll")                                                          \
    for (int r = 0; r < 4; ++r) {                                              \
      float s = 0.f;                                                           \
      _Pragma("unroll")                                                        \
      for (int nt = 0; nt < NT2; ++nt) {                                       \
        float v = acc2[nt][r] + b2v[nt];                                       \
        s += v * v;                                                            \
      }                                                                        \
      s += __shfl_xor(s, 1); s += __shfl_xor(s, 2);                            \
      s += __shfl_xor(s, 4); s += __shfl_xor(s, 8);                            \
      rinv[r] = 1.0f / s;                                                      \
    }                                                                          \
    /* scatter v (fp16) into padded-tril layout (overlays h; WAR is within- */ \
    /* wave through the in-order DS pipe)                                   */ \
    _Pragma("unroll")                                                          \
    for (int r = 0; r < 4; ++r) {                                              \
      int base = (q * 4 + r) * LVSTR;                                          \
      _Pragma("unroll")                                                        \
      for (int nt = 0; nt < NT2; ++nt)                                         \
        if (vok[nt])                                                           \
          (MTBASE)[base + voff[nt]] = (_Float16)(acc2[nt][r] + b2v[nt]);       \
    }                                                                          \
    /* LL^T via MFMA: A-frag == B-frag, one frag per batch row */              \
    _Pragma("unroll")                                                          \
    for (int tq = 0; tq < 4; ++tq)                                             \
      _Pragma("unroll")                                                        \
      for (int r4 = 0; r4 < 4; ++r4) {                                         \
        int t = tq * 4 + r4;                                                   \
        const _Float16* rp = (MTBASE) + t * LVSTR + ro_lm + q * 8;             \
        i2 lo = *(const i2*)rp;                                                \
        i2 hi = *(const i2*)(rp + 4);                                          \
        h8 frag;                                                               \
        ((i2*)&frag)[0] = (i2){lo.x & msk[0], lo.y & msk[1]};                  \
        ((i2*)&frag)[1] = (i2){hi.x & msk[2], hi.y & msk[3]};                  \
        f4 d = __builtin_amdgcn_mfma_f32_16x16x32_f16(frag, frag, zero, 0, 0, 0); \
        float riv = __uint_as_float(                                           \
            __builtin_amdgcn_readlane(__float_as_uint(rinv[r4]), tq * 16));    \
        float* op = out + (size_t)(b0 + (MT) * 64 + w * 16 + t) * 256 + outcol;\
        _Pragma("unroll")                                                      \
        for (int sr = 0; sr < 4; ++sr)                                         \
          op[sr * 16] = d[sr] * riv;   /* full 64B sectors per instr */        \
      }                                                                        \
  } while (0)

// ---------------------------------------------------------------------------
// Fused kernel: 256 threads (4 waves), 128 batch rows/block, NO barrier.
// ---------------------------------------------------------------------------
__global__ __launch_bounds__(256, 4) void fused_mlp(
        const float* __restrict__ x, const float* __restrict__ b1,
        const float* __restrict__ b2, const _Float16* __restrict__ pw1,
        const _Float16* __restrict__ pw2, float* __restrict__ out) {
    __shared__ _Float16 smem[4 * 2 * MTREG] __attribute__((aligned(16)));  // 40960 B

    const int tid  = threadIdx.x;
    const int w    = tid >> 6;
    const int lane = tid & 63;
    const int q    = lane >> 4;
    const int lm   = lane & 15;
    const int b0   = blockIdx.x * BM;

    _Float16* mt0base = smem + w * (2 * MTREG);   // per-wave, per-mt regions
    _Float16* mt1base = mt0base + MTREG;

    const int ro_lm  = rowoff(lm);
    const int outcol = q * 64 + lm;               // (q*4)*16 + lm
    const f4 zero = (f4){0.f, 0.f, 0.f, 0.f};

    // frag masks: element j of the LL^T frag is L[lm][q*8+j], valid iff q*8+j <= lm
    int msk[4];
    {
        int n = lm - q * 8 + 1;
        #pragma unroll
        for (int p = 0; p < 4; ++p) {
            int c2 = n - 2 * p; c2 = c2 < 0 ? 0 : (c2 > 2 ? 2 : c2);
            msk[p] = (c2 == 2) ? ~0 : ((c2 == 1) ? 0xFFFF : 0);
        }
    }

    const float* xr0 = x + (size_t)(b0 + w * 16 + lm) * IN_DIM + q * 8;  // m-tile 0
    const float* xr1 = xr0 + (size_t)64 * IN_DIM;                        // m-tile 1

    f4 xp[8];   // mt1 4-deep x window; first fill issued inside TAIL(mt0)

    // ---------------- GEMM1(mt0): rolling 4-deep x prefetch ----------------
    f4 acc[NT1];
    #pragma unroll
    for (int nt = 0; nt < NT1; ++nt) acc[nt] = (f4){0.f, 0.f, 0.f, 0.f};

    {
        f4 xw[8];   // 4 k-steps in flight (256B/lane)
        #pragma unroll
        for (int k = 0; k < 4; ++k) {
            xw[2 * k]     = *(const f4*)(xr0 + k * 32);
            xw[2 * k + 1] = *(const f4*)(xr0 + k * 32 + 4);
        }

        #pragma unroll
        for (int ks = 0; ks < KS1; ++ks) {
            h8 bf[NT1];
            #pragma unroll
            for (int nt = 0; nt < NT1; ++nt)
                bf[nt] = *(const h8*)(pw1 + ((ks * NT1 + nt) * 64 + lane) * 8);
            h8 af = cvt_h8(xw[(ks & 3) * 2], xw[(ks & 3) * 2 + 1]);
            if (ks + 4 < KS1) {   // refill the window slot just consumed
                xw[(ks & 3) * 2]     = *(const f4*)(xr0 + (ks + 4) * 32);
                xw[(ks & 3) * 2 + 1] = *(const f4*)(xr0 + (ks + 4) * 32 + 4);
            }
            #pragma unroll
            for (int nt = 0; nt < NT1; ++nt)
                acc[nt] = __builtin_amdgcn_mfma_f32_16x16x32_f16(af, bf[nt], acc[nt], 0, 0, 0);
        }
    }

    TAIL(mt0base, 0);   // h->LDS, GEMM2, issue mt1 x window, trace, LL^T, stores

    // ---------------- GEMM1(mt1): consume prefetched x window ----------------
    #pragma unroll
    for (int nt = 0; nt < NT1; ++nt) acc[nt] = (f4){0.f, 0.f, 0.f, 0.f};

    #pragma unroll
    for (int ks = 0; ks < KS1; ++ks) {
        h8 bf[NT1];
        #pragma unroll
        for (int nt = 0; nt < NT1; ++nt)
            bf[nt] = *(const h8*)(pw1 + ((ks * NT1 + nt) * 64 + lane) * 8);
        h8 af = cvt_h8(xp[(ks & 3) * 2], xp[(ks & 3) * 2 + 1]);
        if (ks + 4 < KS1) {   // roll the window like mt0
            xp[(ks & 3) * 2]     = *(const f4*)(xr1 + (ks + 4) * 32);
            xp[(ks & 3) * 2 + 1] = *(const f4*)(xr1 + (ks + 4) * 32 + 4);
        }
        #pragma unroll
        for (int nt = 0; nt < NT1; ++nt)
            acc[nt] = __builtin_amdgcn_mfma_f32_16x16x32_f16(af, bf[nt], acc[nt], 0, 0, 0);
    }

    TAIL(mt1base, 1);
}

extern "C" void kernel_launch(void* const* d_in, const int* in_sizes, int n_in,
                              void* d_out, int out_size, void* d_ws, size_t ws_size,
                              hipStream_t stream) {
    const float* x  = (const float*)d_in[0];
    const float* W1 = (const float*)d_in[1];
    const float* b1 = (const float*)d_in[2];
    const float* W2 = (const float*)d_in[3];
    const float* b2 = (const float*)d_in[4];
    float* out = (float*)d_out;

    _Float16* pw1 = (_Float16*)d_ws;            // 64 KB
    _Float16* pw2 = pw1 + PW1_N;                // 36 KB  (needs ws_size >= 100 KB)

    pack_weights<<<(PW1_N + PW2_N + 255) / 256, 256, 0, stream>>>(W1, W2, pw1, pw2);
    fused_mlp<<<BATCH_N / BM, 256, 0, stream>>>(x, b1, b2, pw1, pw2, out);
}

// Round 3
// 379.078 us; speedup vs baseline: 1.0423x; 1.0423x over previous
//
#include <hip/hip_runtime.h>

// ---------------------------------------------------------------------------
// DensityMatrixMLP: out[b] = (L Lt) / trace(L Lt),  L = tril(relu(x@W1+b1)@W2+b2)
// B=131072, IN=256, HID=128, TRIL=136, D=16.
//
// R2 (verified 95us/dispatch): LL^T via MFMA (A-frag==B-frag identity), but
// phase-locked: all reads in GEMM1, all writes at the end (2.4 TB/s avg).
// R3b FAILED: mt1 x prefetched into regs across the TAIL -> spill (+300 MB
// scratch traffic, 235us). Lesson: no cross-phase register arrays.
// R4: sequential m-tiles WITHOUT the cross-phase prefetch:
//   GEMM1(mt0) -> TAIL(mt0) -> GEMM1(mt1) -> TAIL(mt1). mt1's reads overlap
//   mt0's compute+stores across the ~16 drifting waves/CU; each GEMM1 has a
//   local rolling 4-deep x window (128B/lane in flight). Halves acc AGPRs.
//   + Symmetric float4 stores: rho is symmetric, so lane's d[0..3] (rows
//     q*4+sr, col lm) are also row lm, cols q*4..q*4+3 -> one dwordx4 per
//     LL^T iter (128->32 store instrs/lane, 1KB contiguous per wave-store).
//   + One LDS region per wave (mt1 reuses mt0's; sequential + in-order DS
//     pipe): LDS 40960 -> 20480 B, occupancy can rise to 8 blocks/CU.
// ---------------------------------------------------------------------------

typedef _Float16 h8 __attribute__((ext_vector_type(8)));
typedef float    f4 __attribute__((ext_vector_type(4)));
typedef int      i2 __attribute__((ext_vector_type(2)));

#define BATCH_N 131072
#define IN_DIM  256
#define HID     128
#define TRILN   136
#define BM      128      // batch rows per block (4 waves x 2 sequential m-tiles)
#define NT1     8        // 128/16 n-tiles, GEMM1
#define KS1     8        // 256/32 k-steps, GEMM1
#define NT2     9        // ceil(136/16) n-tiles, GEMM2 (padded with zeros)
#define KS2     4        // 128/32 k-steps, GEMM2
#define HSTR    136      // h LDS row stride (halves) inside the wave region
#define LVSTR   160      // v LDS row stride (halves): 16 tril rows padded to
                         // 4-half multiples -> every L-row starts 8B-aligned
#define MTREG   2560     // halves per wave region: 16 rows x LVSTR
#define PW1_N   (KS1*NT1*64*8)   // 32768 halves = 64 KB
#define PW2_N   (KS2*NT2*64*8)   // 18432 halves = 36 KB

// offset (halves) of tril row i inside a batch row's LVSTR region:
// rows padded to 4*ceil((i+1)/4); closed form via group g=i>>2.
__device__ __forceinline__ int rowoff(int i) {
    int g = i >> 2;
    return 4 * (g + 1) * (2 * g + (i & 3));   // 0,4,8,12,16,24,...,144
}

// ---------------------------------------------------------------------------
// Prelude: pack W1/W2 into MFMA B-fragment order, fp16.
// ---------------------------------------------------------------------------
__global__ void pack_weights(const float* __restrict__ W1,
                             const float* __restrict__ W2,
                             _Float16* __restrict__ pw1,
                             _Float16* __restrict__ pw2) {
    int gid = blockIdx.x * blockDim.x + threadIdx.x;
    if (gid < PW1_N) {
        int j = gid & 7, l = (gid >> 3) & 63, f = gid >> 9;
        int ks = f >> 3, nt = f & 7;
        int k = ks * 32 + (l >> 4) * 8 + j;
        int n = nt * 16 + (l & 15);
        pw1[gid] = (_Float16)W1[k * HID + n];
    } else if (gid < PW1_N + PW2_N) {
        int g = gid - PW1_N;
        int j = g & 7, l = (g >> 3) & 63, f = g >> 9;
        int ks = f / NT2, nt = f - ks * NT2;
        int k = ks * 32 + (l >> 4) * 8 + j;
        int col = nt * 16 + (l & 15);
        pw2[g] = (col < TRILN) ? (_Float16)W2[k * TRILN + col] : (_Float16)0.0f;
    }
}

__device__ __forceinline__ h8 cvt_h8(f4 lo, f4 hi) {
    h8 r;
    r[0] = (_Float16)lo[0]; r[1] = (_Float16)lo[1];
    r[2] = (_Float16)lo[2]; r[3] = (_Float16)lo[3];
    r[4] = (_Float16)hi[0]; r[5] = (_Float16)hi[1];
    r[6] = (_Float16)hi[2]; r[7] = (_Float16)hi[3];
    return r;
}

// ---------------------------------------------------------------------------
// Fused kernel: 256 threads (4 waves), 128 batch rows/block, NO barrier.
// ---------------------------------------------------------------------------
__global__ __launch_bounds__(256, 4) void fused_mlp(
        const float* __restrict__ x, const float* __restrict__ b1,
        const float* __restrict__ b2, const _Float16* __restrict__ pw1,
        const _Float16* __restrict__ pw2, float* __restrict__ out) {
    __shared__ _Float16 smem[4 * MTREG] __attribute__((aligned(16)));  // 20480 B

    const int tid  = threadIdx.x;
    const int w    = tid >> 6;
    const int lane = tid & 63;
    const int q    = lane >> 4;
    const int lm   = lane & 15;
    const int b0   = blockIdx.x * BM;

    _Float16* reg0 = smem + w * MTREG;   // this wave's single region

    const int ro_lm = rowoff(lm);
    const f4 zero = (f4){0.f, 0.f, 0.f, 0.f};

    // frag masks: element j of the LL^T frag is L[lm][q*8+j], valid iff q*8+j <= lm
    int msk[4];
    {
        int n = lm - q * 8 + 1;
        #pragma unroll
        for (int p = 0; p < 4; ++p) {
            int c2 = n - 2 * p; c2 = c2 < 0 ? 0 : (c2 > 2 ? 2 : c2);
            msk[p] = (c2 == 2) ? ~0 : ((c2 == 1) ? 0xFFFF : 0);
        }
    }

    const float* xrw = x + (size_t)(b0 + w * 16 + lm) * IN_DIM + q * 8;

    #pragma unroll
    for (int mt = 0; mt < 2; ++mt) {
        const float* xr = xrw + (size_t)(mt * 64) * IN_DIM;

        // ---------------- GEMM1: rolling 4-deep x prefetch ----------------
        f4 acc[NT1];
        #pragma unroll
        for (int nt = 0; nt < NT1; ++nt) acc[nt] = (f4){0.f, 0.f, 0.f, 0.f};

        {
            f4 xw[8];   // 4 k-steps in flight (128B/lane)
            #pragma unroll
            for (int k = 0; k < 4; ++k) {
                xw[2 * k]     = *(const f4*)(xr + k * 32);
                xw[2 * k + 1] = *(const f4*)(xr + k * 32 + 4);
            }
            #pragma unroll
            for (int ks = 0; ks < KS1; ++ks) {
                h8 bf[NT1];
                #pragma unroll
                for (int nt = 0; nt < NT1; ++nt)
                    bf[nt] = *(const h8*)(pw1 + ((ks * NT1 + nt) * 64 + lane) * 8);
                h8 af = cvt_h8(xw[(ks & 3) * 2], xw[(ks & 3) * 2 + 1]);
                if (ks + 4 < KS1) {   // refill the slot just consumed
                    xw[(ks & 3) * 2]     = *(const f4*)(xr + (ks + 4) * 32);
                    xw[(ks & 3) * 2 + 1] = *(const f4*)(xr + (ks + 4) * 32 + 4);
                }
                #pragma unroll
                for (int nt = 0; nt < NT1; ++nt)
                    acc[nt] = __builtin_amdgcn_mfma_f32_16x16x32_f16(af, bf[nt], acc[nt], 0, 0, 0);
            }
        }

        // ---- bias + relu + store h (own wave's rows -> in-order DS pipe) ----
        #pragma unroll
        for (int nt = 0; nt < NT1; ++nt) {
            float b1v = b1[nt * 16 + lm];
            #pragma unroll
            for (int r = 0; r < 4; ++r) {
                float hv = fmaxf(acc[nt][r] + b1v, 0.f);
                reg0[(q * 4 + r) * HSTR + nt * 16 + lm] = (_Float16)hv;
            }
        }

        // ---------------- GEMM2: v = h @ W2 ----------------
        f4 acc2[NT2];
        #pragma unroll
        for (int nt = 0; nt < NT2; ++nt) acc2[nt] = (f4){0.f, 0.f, 0.f, 0.f};
        #pragma unroll
        for (int ks = 0; ks < KS2; ++ks) {
            h8 ha = *(const h8*)(reg0 + lm * HSTR + ks * 32 + q * 8);
            #pragma unroll
            for (int nt = 0; nt < NT2; ++nt) {
                h8 bf2 = *(const h8*)(pw2 + ((ks * NT2 + nt) * 64 + lane) * 8);
                acc2[nt] = __builtin_amdgcn_mfma_f32_16x16x32_f16(ha, bf2, acc2[nt], 0, 0, 0);
            }
        }

        // ---- bias2 + per-lane tril mapping ----
        float b2v[NT2];
        int voff[NT2]; bool vok[NT2];
        #pragma unroll
        for (int nt = 0; nt < NT2; ++nt) {
            int c = nt * 16 + lm;
            vok[nt] = (c < TRILN);
            int cc = vok[nt] ? c : 0;
            int i = (int)((sqrtf(8.0f * (float)cc + 1.0f) - 1.0f) * 0.5f);
            int k = cc - (i * (i + 1)) / 2;
            voff[nt] = rowoff(i) + k;
            b2v[nt] = vok[nt] ? b2[c] : 0.f;
        }

        // ---- trace partials, reduce across the 16-lane row group ----
        float rinv[4];
        #pragma unroll
        for (int r = 0; r < 4; ++r) {
            float s = 0.f;
            #pragma unroll
            for (int nt = 0; nt < NT2; ++nt) {
                float v = acc2[nt][r] + b2v[nt];
                s += v * v;
            }
            s += __shfl_xor(s, 1); s += __shfl_xor(s, 2);
            s += __shfl_xor(s, 4); s += __shfl_xor(s, 8);
            rinv[r] = 1.0f / s;
        }

        // ---- scatter v (fp16) into padded-tril layout (overlays h; WAR is
        //      within-wave through the in-order DS pipe) ----
        #pragma unroll
        for (int r = 0; r < 4; ++r) {
            int base = (q * 4 + r) * LVSTR;
            #pragma unroll
            for (int nt = 0; nt < NT2; ++nt)
                if (vok[nt])
                    reg0[base + voff[nt]] = (_Float16)(acc2[nt][r] + b2v[nt]);
        }

        // ---- LL^T via MFMA: A-frag == B-frag, one frag per batch row ----
        // D is symmetric: lane's d[sr] = D[q*4+sr][lm] = D[lm][q*4+sr], so the
        // 4 values are consecutive cols of row lm -> one dwordx4 per row.
        #pragma unroll
        for (int tq = 0; tq < 4; ++tq)
            #pragma unroll
            for (int r4 = 0; r4 < 4; ++r4) {
                int t = tq * 4 + r4;
                const _Float16* rp = reg0 + t * LVSTR + ro_lm + q * 8;
                i2 lo = *(const i2*)rp;
                i2 hi = *(const i2*)(rp + 4);
                h8 frag;
                ((i2*)&frag)[0] = (i2){lo.x & msk[0], lo.y & msk[1]};
                ((i2*)&frag)[1] = (i2){hi.x & msk[2], hi.y & msk[3]};
                f4 d = __builtin_amdgcn_mfma_f32_16x16x32_f16(frag, frag, zero, 0, 0, 0);
                float riv = __uint_as_float(
                    __builtin_amdgcn_readlane(__float_as_uint(rinv[r4]), tq * 16));
                f4 dv = d * riv;
                *(f4*)(out + (size_t)(b0 + mt * 64 + w * 16 + t) * 256 + lm * 16 + q * 4) = dv;
            }
    }
}

extern "C" void kernel_launch(void* const* d_in, const int* in_sizes, int n_in,
                              void* d_out, int out_size, void* d_ws, size_t ws_size,
                              hipStream_t stream) {
    const float* x  = (const float*)d_in[0];
    const float* W1 = (const float*)d_in[1];
    const float* b1 = (const float*)d_in[2];
    const float* W2 = (const float*)d_in[3];
    const float* b2 = (const float*)d_in[4];
    float* out = (float*)d_out;

    _Float16* pw1 = (_Float16*)d_ws;            // 64 KB
    _Float16* pw2 = pw1 + PW1_N;                // 36 KB  (needs ws_size >= 100 KB)

    pack_weights<<<(PW1_N + PW2_N + 255) / 256, 256, 0, stream>>>(W1, W2, pw1, pw2);
    fused_mlp<<<BATCH_N / BM, 256, 0, stream>>>(x, b1, b2, pw1, pw2, out);
}

// Round 4
// 374.625 us; speedup vs baseline: 1.0547x; 1.0119x over previous
//
#include <hip/hip_runtime.h>

// ---------------------------------------------------------------------------
// DensityMatrixMLP: out[b] = (L Lt) / trace(L Lt),  L = tril(relu(x@W1+b1)@W2+b2)
// B=131072, IN=256, HID=128, TRIL=136, D=16.
//
// R2 (verified 95us/dispatch): LL^T via MFMA (A-frag==B-frag identity), one
// __syncthreads, phase-locked HBM (2.4 TB/s avg).
// R3b FAILED (235us): mt1 x prefetched across the TAIL -> spill (+300 MB).
// R4 FAILED (210us): removed cross-phase arrays but ALSO removed the last
// barrier -> one giant scheduling region; the list scheduler hoisted mt1's
// x loads + weight fragments across mt0's tail -> same spill (WRITE 322 MB).
// Lesson: R2's __syncthreads was protecting us as a compile-time scheduling
// fence, not as a runtime barrier.
// R5: R4 structure + __builtin_amdgcn_sched_barrier(0) at every phase
// boundary (free at runtime). Per-phase register pressure back to R2 levels;
// inter-wave drift (no runtime barrier anywhere) provides read/write overlap.
// ---------------------------------------------------------------------------

typedef _Float16 h8 __attribute__((ext_vector_type(8)));
typedef float    f4 __attribute__((ext_vector_type(4)));
typedef int      i2 __attribute__((ext_vector_type(2)));

#define BATCH_N 131072
#define IN_DIM  256
#define HID     128
#define TRILN   136
#define BM      128      // batch rows per block (4 waves x 2 sequential m-tiles)
#define NT1     8        // 128/16 n-tiles, GEMM1
#define KS1     8        // 256/32 k-steps, GEMM1
#define NT2     9        // ceil(136/16) n-tiles, GEMM2 (padded with zeros)
#define KS2     4        // 128/32 k-steps, GEMM2
#define HSTR    136      // h LDS row stride (halves) inside the wave region
#define LVSTR   160      // v LDS row stride (halves): 16 tril rows padded to
                         // 4-half multiples -> every L-row starts 8B-aligned
#define MTREG   2560     // halves per wave region: 16 rows x LVSTR
#define PW1_N   (KS1*NT1*64*8)   // 32768 halves = 64 KB
#define PW2_N   (KS2*NT2*64*8)   // 18432 halves = 36 KB

#define FENCE() __builtin_amdgcn_sched_barrier(0)

// offset (halves) of tril row i inside a batch row's LVSTR region:
// rows padded to 4*ceil((i+1)/4); closed form via group g=i>>2.
__device__ __forceinline__ int rowoff(int i) {
    int g = i >> 2;
    return 4 * (g + 1) * (2 * g + (i & 3));   // 0,4,8,12,16,24,...,144
}

// ---------------------------------------------------------------------------
// Prelude: pack W1/W2 into MFMA B-fragment order, fp16.
// ---------------------------------------------------------------------------
__global__ void pack_weights(const float* __restrict__ W1,
                             const float* __restrict__ W2,
                             _Float16* __restrict__ pw1,
                             _Float16* __restrict__ pw2) {
    int gid = blockIdx.x * blockDim.x + threadIdx.x;
    if (gid < PW1_N) {
        int j = gid & 7, l = (gid >> 3) & 63, f = gid >> 9;
        int ks = f >> 3, nt = f & 7;
        int k = ks * 32 + (l >> 4) * 8 + j;
        int n = nt * 16 + (l & 15);
        pw1[gid] = (_Float16)W1[k * HID + n];
    } else if (gid < PW1_N + PW2_N) {
        int g = gid - PW1_N;
        int j = g & 7, l = (g >> 3) & 63, f = g >> 9;
        int ks = f / NT2, nt = f - ks * NT2;
        int k = ks * 32 + (l >> 4) * 8 + j;
        int col = nt * 16 + (l & 15);
        pw2[g] = (col < TRILN) ? (_Float16)W2[k * TRILN + col] : (_Float16)0.0f;
    }
}

__device__ __forceinline__ h8 cvt_h8(f4 lo, f4 hi) {
    h8 r;
    r[0] = (_Float16)lo[0]; r[1] = (_Float16)lo[1];
    r[2] = (_Float16)lo[2]; r[3] = (_Float16)lo[3];
    r[4] = (_Float16)hi[0]; r[5] = (_Float16)hi[1];
    r[6] = (_Float16)hi[2]; r[7] = (_Float16)hi[3];
    return r;
}

// ---------------------------------------------------------------------------
// Fused kernel: 256 threads (4 waves), 128 batch rows/block, NO runtime barrier.
// ---------------------------------------------------------------------------
__global__ __launch_bounds__(256, 4) void fused_mlp(
        const float* __restrict__ x, const float* __restrict__ b1,
        const float* __restrict__ b2, const _Float16* __restrict__ pw1,
        const _Float16* __restrict__ pw2, float* __restrict__ out) {
    __shared__ _Float16 smem[4 * MTREG] __attribute__((aligned(16)));  // 20480 B

    const int tid  = threadIdx.x;
    const int w    = tid >> 6;
    const int lane = tid & 63;
    const int q    = lane >> 4;
    const int lm   = lane & 15;
    const int b0   = blockIdx.x * BM;

    _Float16* reg0 = smem + w * MTREG;   // this wave's single region

    const int ro_lm = rowoff(lm);
    const f4 zero = (f4){0.f, 0.f, 0.f, 0.f};

    // frag masks: element j of the LL^T frag is L[lm][q*8+j], valid iff q*8+j <= lm
    int msk[4];
    {
        int n = lm - q * 8 + 1;
        #pragma unroll
        for (int p = 0; p < 4; ++p) {
            int c2 = n - 2 * p; c2 = c2 < 0 ? 0 : (c2 > 2 ? 2 : c2);
            msk[p] = (c2 == 2) ? ~0 : ((c2 == 1) ? 0xFFFF : 0);
        }
    }

    const float* xrw = x + (size_t)(b0 + w * 16 + lm) * IN_DIM + q * 8;

    #pragma unroll
    for (int mt = 0; mt < 2; ++mt) {
        const float* xr = xrw + (size_t)(mt * 64) * IN_DIM;

        // ---------------- GEMM1: rolling 4-deep x prefetch ----------------
        f4 acc[NT1];
        #pragma unroll
        for (int nt = 0; nt < NT1; ++nt) acc[nt] = (f4){0.f, 0.f, 0.f, 0.f};

        {
            f4 xw[8];   // 4 k-steps in flight (128B/lane)
            #pragma unroll
            for (int k = 0; k < 4; ++k) {
                xw[2 * k]     = *(const f4*)(xr + k * 32);
                xw[2 * k + 1] = *(const f4*)(xr + k * 32 + 4);
            }
            #pragma unroll
            for (int ks = 0; ks < KS1; ++ks) {
                h8 bf[NT1];
                #pragma unroll
                for (int nt = 0; nt < NT1; ++nt)
                    bf[nt] = *(const h8*)(pw1 + ((ks * NT1 + nt) * 64 + lane) * 8);
                h8 af = cvt_h8(xw[(ks & 3) * 2], xw[(ks & 3) * 2 + 1]);
                if (ks + 4 < KS1) {   // refill the slot just consumed
                    xw[(ks & 3) * 2]     = *(const f4*)(xr + (ks + 4) * 32);
                    xw[(ks & 3) * 2 + 1] = *(const f4*)(xr + (ks + 4) * 32 + 4);
                }
                #pragma unroll
                for (int nt = 0; nt < NT1; ++nt)
                    acc[nt] = __builtin_amdgcn_mfma_f32_16x16x32_f16(af, bf[nt], acc[nt], 0, 0, 0);
            }
        }

        FENCE();   // phase boundary: nothing from the tail hoists into GEMM1

        // ---- bias + relu + store h (own wave's rows -> in-order DS pipe) ----
        #pragma unroll
        for (int nt = 0; nt < NT1; ++nt) {
            float b1v = b1[nt * 16 + lm];
            #pragma unroll
            for (int r = 0; r < 4; ++r) {
                float hv = fmaxf(acc[nt][r] + b1v, 0.f);
                reg0[(q * 4 + r) * HSTR + nt * 16 + lm] = (_Float16)hv;
            }
        }

        FENCE();   // h fully written before GEMM2's loads are scheduled

        // ---------------- GEMM2: v = h @ W2 ----------------
        f4 acc2[NT2];
        #pragma unroll
        for (int nt = 0; nt < NT2; ++nt) acc2[nt] = (f4){0.f, 0.f, 0.f, 0.f};
        #pragma unroll
        for (int ks = 0; ks < KS2; ++ks) {
            h8 ha = *(const h8*)(reg0 + lm * HSTR + ks * 32 + q * 8);
            #pragma unroll
            for (int nt = 0; nt < NT2; ++nt) {
                h8 bf2 = *(const h8*)(pw2 + ((ks * NT2 + nt) * 64 + lane) * 8);
                acc2[nt] = __builtin_amdgcn_mfma_f32_16x16x32_f16(ha, bf2, acc2[nt], 0, 0, 0);
            }
        }

        FENCE();   // phase boundary: epilogue doesn't hoist into GEMM2

        // ---- bias2 + per-lane tril mapping ----
        float b2v[NT2];
        int voff[NT2]; bool vok[NT2];
        #pragma unroll
        for (int nt = 0; nt < NT2; ++nt) {
            int c = nt * 16 + lm;
            vok[nt] = (c < TRILN);
            int cc = vok[nt] ? c : 0;
            int i = (int)((sqrtf(8.0f * (float)cc + 1.0f) - 1.0f) * 0.5f);
            int k = cc - (i * (i + 1)) / 2;
            voff[nt] = rowoff(i) + k;
            b2v[nt] = vok[nt] ? b2[c] : 0.f;
        }

        // ---- trace partials, reduce across the 16-lane row group ----
        float rinv[4];
        #pragma unroll
        for (int r = 0; r < 4; ++r) {
            float s = 0.f;
            #pragma unroll
            for (int nt = 0; nt < NT2; ++nt) {
                float v = acc2[nt][r] + b2v[nt];
                s += v * v;
            }
            s += __shfl_xor(s, 1); s += __shfl_xor(s, 2);
            s += __shfl_xor(s, 4); s += __shfl_xor(s, 8);
            rinv[r] = 1.0f / s;
        }

        // ---- scatter v (fp16) into padded-tril layout (overlays h; WAR is
        //      within-wave through the in-order DS pipe) ----
        #pragma unroll
        for (int r = 0; r < 4; ++r) {
            int base = (q * 4 + r) * LVSTR;
            #pragma unroll
            for (int nt = 0; nt < NT2; ++nt)
                if (vok[nt])
                    reg0[base + voff[nt]] = (_Float16)(acc2[nt][r] + b2v[nt]);
        }

        FENCE();   // scatter writes scheduled before LL^T frag reads

        // ---- LL^T via MFMA: A-frag == B-frag, one frag per batch row ----
        // D is symmetric: lane's d[sr] = D[q*4+sr][lm] = D[lm][q*4+sr], so the
        // 4 values are consecutive cols of row lm -> one dwordx4 per row.
        #pragma unroll
        for (int tq = 0; tq < 4; ++tq)
            #pragma unroll
            for (int r4 = 0; r4 < 4; ++r4) {
                int t = tq * 4 + r4;
                const _Float16* rp = reg0 + t * LVSTR + ro_lm + q * 8;
                i2 lo = *(const i2*)rp;
                i2 hi = *(const i2*)(rp + 4);
                h8 frag;
                ((i2*)&frag)[0] = (i2){lo.x & msk[0], lo.y & msk[1]};
                ((i2*)&frag)[1] = (i2){hi.x & msk[2], hi.y & msk[3]};
                f4 d = __builtin_amdgcn_mfma_f32_16x16x32_f16(frag, frag, zero, 0, 0, 0);
                float riv = __uint_as_float(
                    __builtin_amdgcn_readlane(__float_as_uint(rinv[r4]), tq * 16));
                f4 dv = d * riv;
                *(f4*)(out + (size_t)(b0 + mt * 64 + w * 16 + t) * 256 + lm * 16 + q * 4) = dv;
            }

        FENCE();   // mt boundary: mt1's x loads cannot hoist into mt0's tail
    }
}

extern "C" void kernel_launch(void* const* d_in, const int* in_sizes, int n_in,
                              void* d_out, int out_size, void* d_ws, size_t ws_size,
                              hipStream_t stream) {
    const float* x  = (const float*)d_in[0];
    const float* W1 = (const float*)d_in[1];
    const float* b1 = (const float*)d_in[2];
    const float* W2 = (const float*)d_in[3];
    const float* b2 = (const float*)d_in[4];
    float* out = (float*)d_out;

    _Float16* pw1 = (_Float16*)d_ws;            // 64 KB
    _Float16* pw2 = pw1 + PW1_N;                // 36 KB  (needs ws_size >= 100 KB)

    pack_weights<<<(PW1_N + PW2_N + 255) / 256, 256, 0, stream>>>(W1, W2, pw1, pw2);
    fused_mlp<<<BATCH_N / BM, 256, 0, stream>>>(x, b1, b2, pw1, pw2, out);
}

// Round 5
// 263.990 us; speedup vs baseline: 1.4967x; 1.4191x over previous
//
#include <hip/hip_runtime.h>

// ---------------------------------------------------------------------------
// DensityMatrixMLP: out[b] = (L Lt) / trace(L Lt),  L = tril(relu(x@W1+b1)@W2+b2)
// B=131072, IN=256, HID=128, TRIL=136, D=16.
//
// R2 (95us): interleaved m-tiles, LL^T via MFMA, 1 barrier. Latency-bound
// (MFMA 6%, VALU 12%, HBM 29% -- all idle; occupancy 16 waves/CU).
// R3b/R4/R5 FAILED (210-235us): sequential m-tiles spill ~300MB scratch.
// Root cause found in R5 post-mortem: GVN/CSE merges mt0's and mt1's
// IDENTICAL pw1/pw2 fragment loads -> ~400 VGPRs live across mt0's tail.
// sched_barrier can't stop value-liveness extension. R2 was safe because
// interleaved m-tiles consume each fragment immediately.
// R6: eliminate the m-tile dimension instead of sequencing it.
//   BM=64: each wave owns ONE 16-row m-tile; grid 2048 blocks.
//   - No repeated weight-fragment addresses -> no CSE hazard, R2-level
//     per-phase pressure (~64 VGPR + acc).
//   - LDS 20480 B (one 2560-half region/wave) -> up to 8 blocks/CU,
//     up to 32 waves/CU (2x R2) against the measured latency-bound regime.
//   - No runtime barrier (per-wave regions, in-order DS pipe within wave).
//   - Symmetric dwordx4 stores: rho symmetric => lane's d[0..3] (rows
//     q*4+sr, col lm) == row lm, cols q*4+3..q*4 -> one 16B store per row.
//   - sched_barrier(0) at phase boundaries as free pressure insurance.
// ---------------------------------------------------------------------------

typedef _Float16 h8 __attribute__((ext_vector_type(8)));
typedef float    f4 __attribute__((ext_vector_type(4)));
typedef int      i2 __attribute__((ext_vector_type(2)));

#define BATCH_N 131072
#define IN_DIM  256
#define HID     128
#define TRILN   136
#define BM      64       // batch rows per block = 4 waves x ONE 16-row m-tile
#define NT1     8        // 128/16 n-tiles, GEMM1
#define KS1     8        // 256/32 k-steps, GEMM1
#define NT2     9        // ceil(136/16) n-tiles, GEMM2 (padded with zeros)
#define KS2     4        // 128/32 k-steps, GEMM2
#define HSTR    136      // h LDS row stride (halves) inside the wave region
#define LVSTR   160      // v LDS row stride (halves): 16 tril rows padded to
                         // 4-half multiples -> every L-row starts 8B-aligned
#define WREG    2560     // halves per wave region: 16 rows x LVSTR (>16x136)
#define PW1_N   (KS1*NT1*64*8)   // 32768 halves = 64 KB
#define PW2_N   (KS2*NT2*64*8)   // 18432 halves = 36 KB

#define FENCE() __builtin_amdgcn_sched_barrier(0)

// offset (halves) of tril row i inside a batch row's LVSTR region:
// rows padded to 4*ceil((i+1)/4); closed form via group g=i>>2.
__device__ __forceinline__ int rowoff(int i) {
    int g = i >> 2;
    return 4 * (g + 1) * (2 * g + (i & 3));   // 0,4,8,12,16,24,...,144
}

// ---------------------------------------------------------------------------
// Prelude: pack W1/W2 into MFMA B-fragment order, fp16.
// ---------------------------------------------------------------------------
__global__ void pack_weights(const float* __restrict__ W1,
                             const float* __restrict__ W2,
                             _Float16* __restrict__ pw1,
                             _Float16* __restrict__ pw2) {
    int gid = blockIdx.x * blockDim.x + threadIdx.x;
    if (gid < PW1_N) {
        int j = gid & 7, l = (gid >> 3) & 63, f = gid >> 9;
        int ks = f >> 3, nt = f & 7;
        int k = ks * 32 + (l >> 4) * 8 + j;
        int n = nt * 16 + (l & 15);
        pw1[gid] = (_Float16)W1[k * HID + n];
    } else if (gid < PW1_N + PW2_N) {
        int g = gid - PW1_N;
        int j = g & 7, l = (g >> 3) & 63, f = g >> 9;
        int ks = f / NT2, nt = f - ks * NT2;
        int k = ks * 32 + (l >> 4) * 8 + j;
        int col = nt * 16 + (l & 15);
        pw2[g] = (col < TRILN) ? (_Float16)W2[k * TRILN + col] : (_Float16)0.0f;
    }
}

__device__ __forceinline__ h8 cvt_h8(f4 lo, f4 hi) {
    h8 r;
    r[0] = (_Float16)lo[0]; r[1] = (_Float16)lo[1];
    r[2] = (_Float16)lo[2]; r[3] = (_Float16)lo[3];
    r[4] = (_Float16)hi[0]; r[5] = (_Float16)hi[1];
    r[6] = (_Float16)hi[2]; r[7] = (_Float16)hi[3];
    return r;
}

// ---------------------------------------------------------------------------
// Fused kernel: 256 threads (4 waves), 64 batch rows/block, NO runtime barrier.
// ---------------------------------------------------------------------------
__global__ __launch_bounds__(256, 4) void fused_mlp(
        const float* __restrict__ x, const float* __restrict__ b1,
        const float* __restrict__ b2, const _Float16* __restrict__ pw1,
        const _Float16* __restrict__ pw2, float* __restrict__ out) {
    __shared__ _Float16 smem[4 * WREG] __attribute__((aligned(16)));  // 20480 B

    const int tid  = threadIdx.x;
    const int w    = tid >> 6;
    const int lane = tid & 63;
    const int q    = lane >> 4;
    const int lm   = lane & 15;
    const int b0   = blockIdx.x * BM;
    const int rb   = b0 + w * 16;        // this wave's first batch row

    _Float16* reg0 = smem + w * WREG;    // this wave's region

    const int ro_lm = rowoff(lm);
    const f4 zero = (f4){0.f, 0.f, 0.f, 0.f};

    // frag masks: element j of the LL^T frag is L[lm][q*8+j], valid iff q*8+j <= lm
    int msk[4];
    {
        int n = lm - q * 8 + 1;
        #pragma unroll
        for (int p = 0; p < 4; ++p) {
            int c2 = n - 2 * p; c2 = c2 < 0 ? 0 : (c2 > 2 ? 2 : c2);
            msk[p] = (c2 == 2) ? ~0 : ((c2 == 1) ? 0xFFFF : 0);
        }
    }

    const float* xr = x + (size_t)(rb + lm) * IN_DIM + q * 8;

    // ---------------- GEMM1: h = relu(x @ W1 + b1), one m-tile ----------------
    f4 acc[NT1];
    #pragma unroll
    for (int nt = 0; nt < NT1; ++nt) acc[nt] = (f4){0.f, 0.f, 0.f, 0.f};

    {
        f4 xw[8];   // 4 k-steps in flight (128B/lane)
        #pragma unroll
        for (int k = 0; k < 4; ++k) {
            xw[2 * k]     = *(const f4*)(xr + k * 32);
            xw[2 * k + 1] = *(const f4*)(xr + k * 32 + 4);
        }
        #pragma unroll
        for (int ks = 0; ks < KS1; ++ks) {
            h8 bf[NT1];
            #pragma unroll
            for (int nt = 0; nt < NT1; ++nt)
                bf[nt] = *(const h8*)(pw1 + ((ks * NT1 + nt) * 64 + lane) * 8);
            h8 af = cvt_h8(xw[(ks & 3) * 2], xw[(ks & 3) * 2 + 1]);
            if (ks + 4 < KS1) {   // refill the slot just consumed
                xw[(ks & 3) * 2]     = *(const f4*)(xr + (ks + 4) * 32);
                xw[(ks & 3) * 2 + 1] = *(const f4*)(xr + (ks + 4) * 32 + 4);
            }
            #pragma unroll
            for (int nt = 0; nt < NT1; ++nt)
                acc[nt] = __builtin_amdgcn_mfma_f32_16x16x32_f16(af, bf[nt], acc[nt], 0, 0, 0);
        }
    }

    FENCE();   // phase boundary: nothing from the tail hoists into GEMM1

    // ---- bias + relu + store h (own wave's region -> in-order DS pipe) ----
    #pragma unroll
    for (int nt = 0; nt < NT1; ++nt) {
        float b1v = b1[nt * 16 + lm];
        #pragma unroll
        for (int r = 0; r < 4; ++r) {
            float hv = fmaxf(acc[nt][r] + b1v, 0.f);
            reg0[(q * 4 + r) * HSTR + nt * 16 + lm] = (_Float16)hv;
        }
    }

    FENCE();   // h fully scheduled before GEMM2's loads

    // ---------------- GEMM2: v = h @ W2 ----------------
    f4 acc2[NT2];
    #pragma unroll
    for (int nt = 0; nt < NT2; ++nt) acc2[nt] = (f4){0.f, 0.f, 0.f, 0.f};
    #pragma unroll
    for (int ks = 0; ks < KS2; ++ks) {
        h8 ha = *(const h8*)(reg0 + lm * HSTR + ks * 32 + q * 8);
        #pragma unroll
        for (int nt = 0; nt < NT2; ++nt) {
            h8 bf2 = *(const h8*)(pw2 + ((ks * NT2 + nt) * 64 + lane) * 8);
            acc2[nt] = __builtin_amdgcn_mfma_f32_16x16x32_f16(ha, bf2, acc2[nt], 0, 0, 0);
        }
    }

    FENCE();   // phase boundary: epilogue doesn't hoist into GEMM2

    // ---- bias2 + per-lane tril mapping ----
    float b2v[NT2];
    int voff[NT2]; bool vok[NT2];
    #pragma unroll
    for (int nt = 0; nt < NT2; ++nt) {
        int c = nt * 16 + lm;
        vok[nt] = (c < TRILN);
        int cc = vok[nt] ? c : 0;
        int i = (int)((sqrtf(8.0f * (float)cc + 1.0f) - 1.0f) * 0.5f);
        int k = cc - (i * (i + 1)) / 2;
        voff[nt] = rowoff(i) + k;
        b2v[nt] = vok[nt] ? b2[c] : 0.f;
    }

    // ---- trace partials, reduce across the 16-lane row group ----
    float rinv[4];
    #pragma unroll
    for (int r = 0; r < 4; ++r) {
        float s = 0.f;
        #pragma unroll
        for (int nt = 0; nt < NT2; ++nt) {
            float v = acc2[nt][r] + b2v[nt];
            s += v * v;
        }
        s += __shfl_xor(s, 1); s += __shfl_xor(s, 2);
        s += __shfl_xor(s, 4); s += __shfl_xor(s, 8);
        rinv[r] = 1.0f / s;
    }

    // ---- scatter v (fp16) into padded-tril layout (overlays h; WAR is
    //      within-wave through the in-order DS pipe) ----
    #pragma unroll
    for (int r = 0; r < 4; ++r) {
        int base = (q * 4 + r) * LVSTR;
        #pragma unroll
        for (int nt = 0; nt < NT2; ++nt)
            if (vok[nt])
                reg0[base + voff[nt]] = (_Float16)(acc2[nt][r] + b2v[nt]);
    }

    FENCE();   // scatter writes scheduled before LL^T frag reads

    // ---- LL^T via MFMA: A-frag == B-frag, one frag per batch row ----
    // D is symmetric: lane's d[sr] = D[q*4+sr][lm] = D[lm][q*4+sr], so the
    // 4 values are consecutive cols of row lm -> one dwordx4 per row.
    #pragma unroll
    for (int tq = 0; tq < 4; ++tq)
        #pragma unroll
        for (int r4 = 0; r4 < 4; ++r4) {
            int t = tq * 4 + r4;
            const _Float16* rp = reg0 + t * LVSTR + ro_lm + q * 8;
            i2 lo = *(const i2*)rp;
            i2 hi = *(const i2*)(rp + 4);
            h8 frag;
            ((i2*)&frag)[0] = (i2){lo.x & msk[0], lo.y & msk[1]};
            ((i2*)&frag)[1] = (i2){hi.x & msk[2], hi.y & msk[3]};
            f4 d = __builtin_amdgcn_mfma_f32_16x16x32_f16(frag, frag, zero, 0, 0, 0);
            float riv = __uint_as_float(
                __builtin_amdgcn_readlane(__float_as_uint(rinv[r4]), tq * 16));
            f4 dv = d * riv;
            *(f4*)(out + (size_t)(rb + t) * 256 + lm * 16 + q * 4) = dv;
        }
}

extern "C" void kernel_launch(void* const* d_in, const int* in_sizes, int n_in,
                              void* d_out, int out_size, void* d_ws, size_t ws_size,
                              hipStream_t stream) {
    const float* x  = (const float*)d_in[0];
    const float* W1 = (const float*)d_in[1];
    const float* b1 = (const float*)d_in[2];
    const float* W2 = (const float*)d_in[3];
    const float* b2 = (const float*)d_in[4];
    float* out = (float*)d_out;

    _Float16* pw1 = (_Float16*)d_ws;            // 64 KB
    _Float16* pw2 = pw1 + PW1_N;                // 36 KB  (needs ws_size >= 100 KB)

    pack_weights<<<(PW1_N + PW2_N + 255) / 256, 256, 0, stream>>>(W1, W2, pw1, pw2);
    fused_mlp<<<BATCH_N / BM, 256, 0, stream>>>(x, b1, b2, pw1, pw2, out);
}

// Round 6
// 254.533 us; speedup vs baseline: 1.5523x; 1.0372x over previous
//
#include <hip/hip_runtime.h>

// ---------------------------------------------------------------------------
// DensityMatrixMLP: out[b] = (L Lt) / trace(L Lt),  L = tril(relu(x@W1+b1)@W2+b2)
// B=131072, IN=256, HID=128, TRIL=136, D=16.
//
// History: R2 (95us) interleaved 2 m-tiles/wave, 1 barrier. R3b/R4/R5 failed:
// sequential m-tiles -> CSE keeps both tiles' weight fragments live -> spill.
// R6 (101us): BM=64, spill gone, but per-row VMEM traffic UP (weights
// amortized over 16 rows not 32) and occupancy didn't rise (capped ~40%
// regardless of LDS). Key datum: x fully L3-warm gives the SAME dur ->
// not HBM-read-bound; bound by fragment-load/MFMA dependency stalls.
// R7: consolidate. R2's interleaved m-tiles (fragment loaded once -> 2 MFMAs,
// halves weight-load count per row, 2 indep dep-chains) + R6's wins:
//   - symmetric dwordx4 stores (rho symmetric: lane's d[0..3] = row lm,
//     cols q*4..q*4+3 -> one 16B store per row; 32 vs 128 store instrs)
//   - no runtime barrier: per-wave per-mt LDS regions, in-order DS pipe
//   - sched_barrier(0) phase fences (free) to contain per-phase pressure
// ---------------------------------------------------------------------------

typedef _Float16 h8 __attribute__((ext_vector_type(8)));
typedef float    f4 __attribute__((ext_vector_type(4)));
typedef int      i2 __attribute__((ext_vector_type(2)));

#define BATCH_N 131072
#define IN_DIM  256
#define HID     128
#define TRILN   136
#define BM      128      // batch rows per block (4 waves x 2 interleaved m-tiles)
#define NT1     8        // 128/16 n-tiles, GEMM1
#define KS1     8        // 256/32 k-steps, GEMM1
#define NT2     9        // ceil(136/16) n-tiles, GEMM2 (padded with zeros)
#define KS2     4        // 128/32 k-steps, GEMM2
#define HSTR    136      // h LDS row stride (halves) inside an mt region
#define LVSTR   160      // v LDS row stride (halves): 16 tril rows padded to
                         // 4-half multiples -> every L-row starts 8B-aligned
#define MTREG   2560     // halves per (wave,mt) region: 16 rows x LVSTR
#define PW1_N   (KS1*NT1*64*8)   // 32768 halves = 64 KB
#define PW2_N   (KS2*NT2*64*8)   // 18432 halves = 36 KB

#define FENCE() __builtin_amdgcn_sched_barrier(0)

// offset (halves) of tril row i inside a batch row's LVSTR region:
// rows padded to 4*ceil((i+1)/4); closed form via group g=i>>2.
__device__ __forceinline__ int rowoff(int i) {
    int g = i >> 2;
    return 4 * (g + 1) * (2 * g + (i & 3));   // 0,4,8,12,16,24,...,144
}

// ---------------------------------------------------------------------------
// Prelude: pack W1/W2 into MFMA B-fragment order, fp16.
// ---------------------------------------------------------------------------
__global__ void pack_weights(const float* __restrict__ W1,
                             const float* __restrict__ W2,
                             _Float16* __restrict__ pw1,
                             _Float16* __restrict__ pw2) {
    int gid = blockIdx.x * blockDim.x + threadIdx.x;
    if (gid < PW1_N) {
        int j = gid & 7, l = (gid >> 3) & 63, f = gid >> 9;
        int ks = f >> 3, nt = f & 7;
        int k = ks * 32 + (l >> 4) * 8 + j;
        int n = nt * 16 + (l & 15);
        pw1[gid] = (_Float16)W1[k * HID + n];
    } else if (gid < PW1_N + PW2_N) {
        int g = gid - PW1_N;
        int j = g & 7, l = (g >> 3) & 63, f = g >> 9;
        int ks = f / NT2, nt = f - ks * NT2;
        int k = ks * 32 + (l >> 4) * 8 + j;
        int col = nt * 16 + (l & 15);
        pw2[g] = (col < TRILN) ? (_Float16)W2[k * TRILN + col] : (_Float16)0.0f;
    }
}

__device__ __forceinline__ h8 cvt_h8(f4 lo, f4 hi) {
    h8 r;
    r[0] = (_Float16)lo[0]; r[1] = (_Float16)lo[1];
    r[2] = (_Float16)lo[2]; r[3] = (_Float16)lo[3];
    r[4] = (_Float16)hi[0]; r[5] = (_Float16)hi[1];
    r[6] = (_Float16)hi[2]; r[7] = (_Float16)hi[3];
    return r;
}

// ---------------------------------------------------------------------------
// Fused kernel: 256 threads (4 waves), 128 batch rows/block, NO runtime barrier.
// ---------------------------------------------------------------------------
__global__ __launch_bounds__(256, 4) void fused_mlp(
        const float* __restrict__ x, const float* __restrict__ b1,
        const float* __restrict__ b2, const _Float16* __restrict__ pw1,
        const _Float16* __restrict__ pw2, float* __restrict__ out) {
    __shared__ _Float16 smem[4 * 2 * MTREG] __attribute__((aligned(16)));  // 40960 B

    const int tid  = threadIdx.x;
    const int w    = tid >> 6;
    const int lane = tid & 63;
    const int q    = lane >> 4;
    const int lm   = lane & 15;
    const int b0   = blockIdx.x * BM;

    _Float16* reg[2];
    reg[0] = smem + w * (2 * MTREG);   // per-wave, per-mt regions
    reg[1] = reg[0] + MTREG;

    const int ro_lm = rowoff(lm);
    const f4 zero = (f4){0.f, 0.f, 0.f, 0.f};

    // frag masks: element j of the LL^T frag is L[lm][q*8+j], valid iff q*8+j <= lm
    int msk[4];
    {
        int n = lm - q * 8 + 1;
        #pragma unroll
        for (int p = 0; p < 4; ++p) {
            int c2 = n - 2 * p; c2 = c2 < 0 ? 0 : (c2 > 2 ? 2 : c2);
            msk[p] = (c2 == 2) ? ~0 : ((c2 == 1) ? 0xFFFF : 0);
        }
    }

    // ---------------- GEMM1: h = relu(x @ W1 + b1), interleaved m-tiles ------
    f4 acc1[2][NT1];
    #pragma unroll
    for (int mt = 0; mt < 2; ++mt)
        #pragma unroll
        for (int nt = 0; nt < NT1; ++nt)
            acc1[mt][nt] = (f4){0.f, 0.f, 0.f, 0.f};

    const float* xr0 = x + (size_t)(b0 + w * 16 + lm) * IN_DIM + q * 8;  // m-tile 0
    const float* xr1 = xr0 + (size_t)64 * IN_DIM;                        // m-tile 1

    f4 a0l = *(const f4*)xr0, a0h = *(const f4*)(xr0 + 4);
    f4 a1l = *(const f4*)xr1, a1h = *(const f4*)(xr1 + 4);

    #pragma unroll
    for (int ks = 0; ks < KS1; ++ks) {
        h8 bf[NT1];
        #pragma unroll
        for (int nt = 0; nt < NT1; ++nt)
            bf[nt] = *(const h8*)(pw1 + ((ks * NT1 + nt) * 64 + lane) * 8);
        h8 af0 = cvt_h8(a0l, a0h);
        h8 af1 = cvt_h8(a1l, a1h);
        if (ks + 1 < KS1) {  // prefetch next k-step of x (the HBM stream)
            const float* p0 = xr0 + (ks + 1) * 32;
            const float* p1 = xr1 + (ks + 1) * 32;
            a0l = *(const f4*)p0; a0h = *(const f4*)(p0 + 4);
            a1l = *(const f4*)p1; a1h = *(const f4*)(p1 + 4);
        }
        #pragma unroll
        for (int nt = 0; nt < NT1; ++nt) {
            acc1[0][nt] = __builtin_amdgcn_mfma_f32_16x16x32_f16(af0, bf[nt], acc1[0][nt], 0, 0, 0);
            acc1[1][nt] = __builtin_amdgcn_mfma_f32_16x16x32_f16(af1, bf[nt], acc1[1][nt], 0, 0, 0);
        }
    }

    FENCE();   // phase boundary

    // ---- bias + relu + store h to per-(wave,mt) regions (in-order DS pipe) ----
    {
        float b1v[NT1];
        #pragma unroll
        for (int nt = 0; nt < NT1; ++nt) b1v[nt] = b1[nt * 16 + lm];
        #pragma unroll
        for (int mt = 0; mt < 2; ++mt)
            #pragma unroll
            for (int nt = 0; nt < NT1; ++nt)
                #pragma unroll
                for (int r = 0; r < 4; ++r) {
                    float hv = fmaxf(acc1[mt][nt][r] + b1v[nt], 0.f);
                    reg[mt][(q * 4 + r) * HSTR + nt * 16 + lm] = (_Float16)hv;
                }
    }

    FENCE();   // h scheduled before GEMM2 loads

    // ---------------- GEMM2: v = h @ W2, interleaved m-tiles ----------------
    f4 acc2[2][NT2];
    #pragma unroll
    for (int mt = 0; mt < 2; ++mt)
        #pragma unroll
        for (int nt = 0; nt < NT2; ++nt)
            acc2[mt][nt] = (f4){0.f, 0.f, 0.f, 0.f};

    #pragma unroll
    for (int ks = 0; ks < KS2; ++ks) {
        h8 ha0 = *(const h8*)(reg[0] + lm * HSTR + ks * 32 + q * 8);
        h8 ha1 = *(const h8*)(reg[1] + lm * HSTR + ks * 32 + q * 8);
        #pragma unroll
        for (int nt = 0; nt < NT2; ++nt) {
            h8 bf2 = *(const h8*)(pw2 + ((ks * NT2 + nt) * 64 + lane) * 8);
            acc2[0][nt] = __builtin_amdgcn_mfma_f32_16x16x32_f16(ha0, bf2, acc2[0][nt], 0, 0, 0);
            acc2[1][nt] = __builtin_amdgcn_mfma_f32_16x16x32_f16(ha1, bf2, acc2[1][nt], 0, 0, 0);
        }
    }

    FENCE();   // epilogue doesn't hoist into GEMM2

    // ---- bias2 + per-lane tril mapping (shared by both m-tiles) ----
    float b2v[NT2];
    int voff[NT2]; bool vok[NT2];
    #pragma unroll
    for (int nt = 0; nt < NT2; ++nt) {
        int c = nt * 16 + lm;
        vok[nt] = (c < TRILN);
        int cc = vok[nt] ? c : 0;
        int i = (int)((sqrtf(8.0f * (float)cc + 1.0f) - 1.0f) * 0.5f);
        int k = cc - (i * (i + 1)) / 2;
        voff[nt] = rowoff(i) + k;
        b2v[nt] = vok[nt] ? b2[c] : 0.f;
    }

    // ---- trace partials, reduce across the 16-lane row group ----
    float rinv[2][4];
    #pragma unroll
    for (int mt = 0; mt < 2; ++mt)
        #pragma unroll
        for (int r = 0; r < 4; ++r) {
            float s = 0.f;
            #pragma unroll
            for (int nt = 0; nt < NT2; ++nt) {
                float v = acc2[mt][nt][r] + b2v[nt];
                s += v * v;
            }
            s += __shfl_xor(s, 1); s += __shfl_xor(s, 2);
            s += __shfl_xor(s, 4); s += __shfl_xor(s, 8);
            rinv[mt][r] = 1.0f / s;
        }

    // ---- scatter v (fp16) into padded-tril layout (overlays h; WAR within-
    //      wave through the in-order DS pipe) ----
    #pragma unroll
    for (int mt = 0; mt < 2; ++mt)
        #pragma unroll
        for (int r = 0; r < 4; ++r) {
            int base = (q * 4 + r) * LVSTR;
            #pragma unroll
            for (int nt = 0; nt < NT2; ++nt)
                if (vok[nt])
                    reg[mt][base + voff[nt]] = (_Float16)(acc2[mt][nt][r] + b2v[nt]);
        }

    FENCE();   // scatter scheduled before LL^T frag reads

    // ---- LL^T via MFMA: A-frag == B-frag, one frag per batch row ----
    // D symmetric: lane's d[sr] = D[q*4+sr][lm] = D[lm][q*4+sr] -> the 4
    // values are consecutive cols of row lm -> one dwordx4 store per row.
    #pragma unroll
    for (int mt = 0; mt < 2; ++mt)
        #pragma unroll
        for (int tq = 0; tq < 4; ++tq)
            #pragma unroll
            for (int r4 = 0; r4 < 4; ++r4) {
                int t = tq * 4 + r4;
                const _Float16* rp = reg[mt] + t * LVSTR + ro_lm + q * 8;
                i2 lo = *(const i2*)rp;
                i2 hi = *(const i2*)(rp + 4);
                h8 frag;
                ((i2*)&frag)[0] = (i2){lo.x & msk[0], lo.y & msk[1]};
                ((i2*)&frag)[1] = (i2){hi.x & msk[2], hi.y & msk[3]};
                f4 d = __builtin_amdgcn_mfma_f32_16x16x32_f16(frag, frag, zero, 0, 0, 0);
                float riv = __uint_as_float(
                    __builtin_amdgcn_readlane(__float_as_uint(rinv[mt][r4]), tq * 16));
                f4 dv = d * riv;
                *(f4*)(out + (size_t)(b0 + mt * 64 + w * 16 + t) * 256 + lm * 16 + q * 4) = dv;
            }
}

extern "C" void kernel_launch(void* const* d_in, const int* in_sizes, int n_in,
                              void* d_out, int out_size, void* d_ws, size_t ws_size,
                              hipStream_t stream) {
    const float* x  = (const float*)d_in[0];
    const float* W1 = (const float*)d_in[1];
    const float* b1 = (const float*)d_in[2];
    const float* W2 = (const float*)d_in[3];
    const float* b2 = (const float*)d_in[4];
    float* out = (float*)d_out;

    _Float16* pw1 = (_Float16*)d_ws;            // 64 KB
    _Float16* pw2 = pw1 + PW1_N;                // 36 KB  (needs ws_size >= 100 KB)

    pack_weights<<<(PW1_N + PW2_N + 255) / 256, 256, 0, stream>>>(W1, W2, pw1, pw2);
    fused_mlp<<<BATCH_N / BM, 256, 0, stream>>>(x, b1, b2, pw1, pw2, out);
}